// Round 2
// baseline (1882.690 us; speedup 1.0000x reference)
//
#include <hip/hip_runtime.h>
#include <cstdio>

// Problem constants
#define BATCH 256
#define SEQL 256
#define NPOS 259            // 3 + SEQL
#define TTOK (BATCH*NPOS)   // 66304, divisible by 64 (1036 tiles)
#define HD 128
#define NHEAD 8
#define FF 512
#define DEPTH 4
#define CVOC 50001

typedef unsigned short u16;
typedef unsigned int u32;
typedef __bf16 bf16x8 __attribute__((ext_vector_type(8)));
typedef float f32x4 __attribute__((ext_vector_type(4)));

__device__ __forceinline__ u16 f2bf(float f) {
  u32 i = __float_as_uint(f);
  u32 r = (i + 0x7FFFu + ((i >> 16) & 1u)) >> 16;   // RNE
  return (u16)r;
}
__device__ __forceinline__ void cvt8(uint4 u, float* f) {
  f[0] = __uint_as_float(u.x << 16); f[1] = __uint_as_float(u.x & 0xFFFF0000u);
  f[2] = __uint_as_float(u.y << 16); f[3] = __uint_as_float(u.y & 0xFFFF0000u);
  f[4] = __uint_as_float(u.z << 16); f[5] = __uint_as_float(u.z & 0xFFFF0000u);
  f[6] = __uint_as_float(u.w << 16); f[7] = __uint_as_float(u.w & 0xFFFF0000u);
}

// ---------------------------------------------------------------- transpose + downcast
// in (fp32): [D][K][N] -> out (bf16): [D][N][K]
__global__ void k_transpose(const float* __restrict__ in, u16* __restrict__ out,
                            int D, int K, int N) {
  int idx = blockIdx.x * 256 + threadIdx.x;
  int total = D * K * N;
  if (idx >= total) return;
  int k = idx % K; int rem = idx / K; int n = rem % N; int d = rem / N;
  out[idx] = f2bf(in[(d * K + k) * N + n]);
}

// ---------------------------------------------------------------- build x
// grid (NPOS, BATCH), 128 threads. x fp32 [TTOK][128]
__global__ __launch_bounds__(128)
void k_build(const int* __restrict__ item_seq, const int* __restrict__ act_seq,
             const int* __restrict__ tdiff,
             const int* __restrict__ ucv, const int* __restrict__ ucl, const float* __restrict__ unum,
             const int* __restrict__ icv, const int* __restrict__ icl, const float* __restrict__ inum,
             const float* __restrict__ item_t, const float* __restrict__ act_t,
             const float* __restrict__ time_t, const float* __restrict__ cat_t,
             const float* __restrict__ numW, const float* __restrict__ gtok,
             float* __restrict__ x) {
  int pos = blockIdx.x, b = blockIdx.y, h = threadIdx.x;
  float v;
  if (pos == 0) {
    v = gtok[h];
  } else if (pos <= 2) {
    const int* cv = (pos == 1) ? ucv : icv;
    const int* cl = (pos == 1) ? ucl : icl;
    const float* nm = (pos == 1) ? unum : inum;
    float acc = 0.f;
    for (int f = 0; f < 8; ++f) {
      float s = 0.f;
      for (int k = 0; k < 8; ++k) {
        int idx = cv[(b * 8 + f) * 8 + k];          // 0 beyond len; table row0==0
        s += cat_t[((size_t)f * CVOC + idx) * HD + h];
      }
      acc += s / (float)cl[b * 8 + f];
    }
    for (int f = 0; f < 4; ++f)
      for (int d = 0; d < 32; ++d)
        acc += nm[(b * 4 + f) * 32 + d] * numW[(f * 32 + d) * HD + h];
    v = acc * (1.f / 12.f);                          // /(NCAT+NNUM)
  } else {
    int l = pos - 3;
    v = item_t[(size_t)item_seq[b * SEQL + l] * HD + h]
      + act_t[(size_t)act_seq[b * SEQL + l] * HD + h]
      + time_t[(size_t)tdiff[b * SEQL + l] * HD + h];
  }
  x[((size_t)b * NPOS + pos) * HD + h] = v;
}

// ---------------------------------------------------------------- layernorm
// grid TTOK/4, 256 threads: one wave per token, 2 elems/lane. out bf16.
__global__ __launch_bounds__(256)
void k_ln(const float* __restrict__ x, const float* __restrict__ g,
          const float* __restrict__ be, u16* __restrict__ out) {
  int t = blockIdx.x * 4 + (threadIdx.x >> 6);
  int lane = threadIdx.x & 63;
  const float* xr = x + (size_t)t * HD;
  float a = xr[lane], c = xr[lane + 64];
  float s = a + c, s2 = a * a + c * c;
  #pragma unroll
  for (int o = 32; o; o >>= 1) { s += __shfl_xor(s, o); s2 += __shfl_xor(s2, o); }
  float mean = s * (1.f / HD);
  float var = s2 * (1.f / HD) - mean * mean;
  float rstd = rsqrtf(var + 1e-5f);
  out[(size_t)t * HD + lane]      = f2bf((a - mean) * rstd * g[lane] + be[lane]);
  out[(size_t)t * HD + lane + 64] = f2bf((c - mean) * rstd * g[lane + 64] + be[lane + 64]);
}

// ---------------------------------------------------------------- GEMM (MFMA)
// Y[T x N] = act(X[T x K] @ W[K x N] + bias); W given transposed+bf16 WT[N][K].
// tile 64x64, 4 waves x 16 rows. ACT: 0=none, 1=exact gelu. RESID: += into fp32.
template <int ACT, bool RESID>
__global__ __launch_bounds__(256)
void k_gemm(const u16* __restrict__ X, const u16* __restrict__ WT,
            const float* __restrict__ bias, void* __restrict__ outp,
            int K, int N) {
  __shared__ __align__(16) u16 lA[64 * 40];
  __shared__ __align__(16) u16 lB[64 * 40];
  const int tid = threadIdx.x;
  const int wave = tid >> 6, lane = tid & 63;
  const int row0 = blockIdx.x * 64;
  const int n0 = blockIdx.y * 64;
  const int srow = tid >> 2, scg = (tid & 3) * 8;
  const int fr = lane & 15, kg = (lane >> 4) * 8;
  f32x4 acc[4] = {};
  for (int k0 = 0; k0 < K; k0 += 32) {
    __syncthreads();
    *(uint4*)&lA[srow * 40 + scg] = *(const uint4*)&X[(size_t)(row0 + srow) * K + k0 + scg];
    *(uint4*)&lB[srow * 40 + scg] = *(const uint4*)&WT[(size_t)(n0 + srow) * K + k0 + scg];
    __syncthreads();
    bf16x8 afrag = *(const bf16x8*)&lA[(wave * 16 + fr) * 40 + kg];
    #pragma unroll
    for (int c = 0; c < 4; ++c) {
      bf16x8 bfrag = *(const bf16x8*)&lB[(c * 16 + fr) * 40 + kg];
      acc[c] = __builtin_amdgcn_mfma_f32_16x16x32_bf16(afrag, bfrag, acc[c], 0, 0, 0);
    }
  }
  const int rg = (lane >> 4) * 4;
  #pragma unroll
  for (int c = 0; c < 4; ++c) {
    int col = n0 + c * 16 + fr;
    float bv = bias[col];
    #pragma unroll
    for (int j = 0; j < 4; ++j) {
      int row = row0 + wave * 16 + rg + j;
      float v = acc[c][j] + bv;
      if (ACT == 1) v = 0.5f * v * (1.f + erff(v * 0.70710678118654752f));
      if (RESID) ((float*)outp)[(size_t)row * N + col] += v;
      else ((u16*)outp)[(size_t)row * N + col] = f2bf(v);
    }
  }
}

// ---------------------------------------------------------------- attention
// grid (NHEAD, BATCH), 256 threads. qkv: [T][384] bf16, cols = s*128 + h*16 + i.
// online softmax per q-row per thread; keys limited to valid prefix.
__global__ __launch_bounds__(256)
void k_attn(const u16* __restrict__ qkv, const int* __restrict__ mask,
            u16* __restrict__ out) {
  int h = blockIdx.x, b = blockIdx.y;
  __shared__ __align__(16) u16 Ks[NPOS * 16];
  __shared__ __align__(16) u16 Vs[NPOS * 16];
  __shared__ int part[4];
  int tid = threadIdx.x;
  int mv = (mask[b * SEQL + tid] != 0) ? 1 : 0;
  #pragma unroll
  for (int o = 32; o; o >>= 1) mv += __shfl_xor(mv, o);
  if ((tid & 63) == 0) part[tid >> 6] = mv;
  for (int e = tid; e < NPOS * 16; e += 256) {
    int r = e >> 4, i = e & 15;
    size_t base = ((size_t)(b * NPOS + r)) * 384 + h * 16 + i;
    Ks[e] = qkv[base + 128];
    Vs[e] = qkv[base + 256];
  }
  __syncthreads();
  int nvalid = part[0] + part[1] + part[2] + part[3] + 3;
  for (int r = tid; r < NPOS; r += 256) {
    const u16* qp = &qkv[((size_t)(b * NPOS + r)) * 384 + h * 16];
    float q[16];
    {
      uint4 q0 = *(const uint4*)&qp[0], q1 = *(const uint4*)&qp[8];
      cvt8(q0, q); cvt8(q1, q + 8);
      #pragma unroll
      for (int i = 0; i < 16; ++i) q[i] *= 0.25f;   // SCALE = (128/8)^-0.5
    }
    float m = -1e30f, lsum = 0.f, acc[16] = {};
    for (int j = 0; j < nvalid; ++j) {
      uint4 k0 = *(const uint4*)&Ks[j * 16], k1 = *(const uint4*)&Ks[j * 16 + 8];
      float kf[16]; cvt8(k0, kf); cvt8(k1, kf + 8);
      float s = 0.f;
      #pragma unroll
      for (int i = 0; i < 16; ++i) s += q[i] * kf[i];
      if (s > m) {
        float f = __expf(m - s);
        lsum *= f;
        #pragma unroll
        for (int i = 0; i < 16; ++i) acc[i] *= f;
        m = s;
      }
      float e = __expf(s - m);
      lsum += e;
      uint4 v0 = *(const uint4*)&Vs[j * 16], v1 = *(const uint4*)&Vs[j * 16 + 8];
      float vf[16]; cvt8(v0, vf); cvt8(v1, vf + 8);
      #pragma unroll
      for (int i = 0; i < 16; ++i) acc[i] += e * vf[i];
    }
    u16* op = &out[((size_t)(b * NPOS + r)) * HD + h * 16];
    float inv = 1.f / lsum;
    #pragma unroll
    for (int i = 0; i < 16; ++i) op[i] = f2bf(acc[i] * inv);
  }
}

// ---------------------------------------------------------------- head
// grid BATCH, 128 threads. logits[b] then embed[b][h], fp32 out.
__global__ __launch_bounds__(128)
void k_head(const float* __restrict__ x, const float* __restrict__ bw,
            const float* __restrict__ bb, const float* __restrict__ cw,
            const float* __restrict__ cb, float* __restrict__ dout) {
  int b = blockIdx.x, n = threadIdx.x;
  __shared__ float lat[HD];
  __shared__ float redp[2], redss[2];
  float lv = x[((size_t)b * NPOS) * HD + n];
  lat[n] = lv;
  __syncthreads();
  float t = 0.f;
  for (int k = 0; k < HD; ++k) t += lat[k] * bw[k * HD + n];
  t += bb[n];
  t = fmaxf(t, 0.f);
  float p = t * cw[n];
  float ss = lv * lv;
  #pragma unroll
  for (int o = 32; o; o >>= 1) { p += __shfl_xor(p, o); ss += __shfl_xor(ss, o); }
  if ((n & 63) == 0) { redp[n >> 6] = p; redss[n >> 6] = ss; }
  __syncthreads();
  float psum = redp[0] + redp[1];
  float ssum = redss[0] + redss[1];
  if (n == 0) dout[b] = psum + cb[0];
  float nrm = fmaxf(sqrtf(ssum), 1e-12f);
  dout[256 + (size_t)b * HD + n] = lv / nrm;
}

// ---------------------------------------------------------------- launch
extern "C" void kernel_launch(void* const* d_in, const int* in_sizes, int n_in,
                              void* d_out, int out_size, void* d_ws, size_t ws_size,
                              hipStream_t stream) {
  const int* item_seq = (const int*)d_in[0];
  const int* action_seq = (const int*)d_in[1];
  const int* time_diff = (const int*)d_in[2];
  const int* mask = (const int*)d_in[3];
  const int* u_cv = (const int*)d_in[4];
  const int* u_cl = (const int*)d_in[5];
  const float* u_num = (const float*)d_in[6];
  const int* i_cv = (const int*)d_in[7];
  const int* i_cl = (const int*)d_in[8];
  const float* i_num = (const float*)d_in[9];
  const float* item_t = (const float*)d_in[10];
  const float* act_t = (const float*)d_in[11];
  const float* time_t = (const float*)d_in[12];
  const float* cat_t = (const float*)d_in[13];
  const float* num_W = (const float*)d_in[14];
  const float* gtok = (const float*)d_in[15];
  const float* ln1_g = (const float*)d_in[16];
  const float* ln1_b = (const float*)d_in[17];
  const float* qkv_w = (const float*)d_in[18];
  const float* qkv_b = (const float*)d_in[19];
  const float* out_w = (const float*)d_in[20];
  const float* out_b = (const float*)d_in[21];
  const float* w1 = (const float*)d_in[22];
  const float* b1 = (const float*)d_in[23];
  const float* w2 = (const float*)d_in[24];
  const float* b2 = (const float*)d_in[25];
  const float* ln2_g = (const float*)d_in[26];
  const float* ln2_b = (const float*)d_in[27];
  const float* bott_w = (const float*)d_in[28];
  const float* bott_b = (const float*)d_in[29];
  const float* cls_w = (const float*)d_in[30];
  const float* cls_b = (const float*)d_in[31];

  // workspace layout (bytes)
  const size_t off_x   = 0;                    // TTOK*128 f32  = 33,947,648
  const size_t off_src = 33947648;             // TTOK*128 bf16 = 16,973,824 (src / attnout)
  const size_t off_big = 50921472;             // TTOK*512 bf16 = 67,895,296 (qkv / h1)
  const size_t off_wT  = 118816768;            // 786,432 elems bf16
  const size_t need    = 120389632;
  if (ws_size < need) {
    fprintf(stderr, "kernel_launch: ws_size %zu < needed %zu\n", ws_size, need);
    return;
  }
  char* ws = (char*)d_ws;
  float* x   = (float*)(ws + off_x);
  u16* src   = (u16*)(ws + off_src);
  u16* big   = (u16*)(ws + off_big);
  u16* wT    = (u16*)(ws + off_wT);
  u16* qkvT  = wT;                 // [4][384][128]
  u16* outT  = wT + 196608;        // [4][128][128]
  u16* w1T   = wT + 262144;        // [4][512][128]
  u16* w2T   = wT + 524288;        // [4][128][512]

  k_transpose<<<(4 * 128 * 384 + 255) / 256, 256, 0, stream>>>(qkv_w, qkvT, 4, 128, 384);
  k_transpose<<<(4 * 128 * 128 + 255) / 256, 256, 0, stream>>>(out_w, outT, 4, 128, 128);
  k_transpose<<<(4 * 128 * 512 + 255) / 256, 256, 0, stream>>>(w1, w1T, 4, 128, 512);
  k_transpose<<<(4 * 512 * 128 + 255) / 256, 256, 0, stream>>>(w2, w2T, 4, 512, 128);

  k_build<<<dim3(NPOS, BATCH), 128, 0, stream>>>(
      item_seq, action_seq, time_diff, u_cv, u_cl, u_num, i_cv, i_cl, i_num,
      item_t, act_t, time_t, cat_t, num_W, gtok, x);

  const int rt = TTOK / 64;  // 1036
  for (int dd = 0; dd < DEPTH; ++dd) {
    k_ln<<<TTOK / 4, 256, 0, stream>>>(x, ln1_g + dd * HD, ln1_b + dd * HD, src);
    k_gemm<0, false><<<dim3(rt, 6), 256, 0, stream>>>(src, qkvT + dd * 49152, qkv_b + dd * 384, big, 128, 384);
    k_attn<<<dim3(NHEAD, BATCH), 256, 0, stream>>>(big, mask, src);
    k_gemm<0, true><<<dim3(rt, 2), 256, 0, stream>>>(src, outT + dd * 16384, out_b + dd * HD, x, 128, 128);
    k_ln<<<TTOK / 4, 256, 0, stream>>>(x, ln2_g + dd * HD, ln2_b + dd * HD, src);
    k_gemm<1, false><<<dim3(rt, 8), 256, 0, stream>>>(src, w1T + dd * 65536, b1 + dd * FF, big, 128, 512);
    k_gemm<0, true><<<dim3(rt, 2), 256, 0, stream>>>(big, w2T + dd * 65536, b2 + dd * HD, x, 512, 128);
  }

  k_head<<<BATCH, 128, 0, stream>>>(x, bott_w, bott_b, cls_w, cls_b, (float*)d_out);
}

// Round 3
// 1108.771 us; speedup vs baseline: 1.6980x; 1.6980x over previous
//
#include <hip/hip_runtime.h>
#include <cstdio>

// Problem constants
#define BATCH 256
#define SEQL 256
#define NPOS 259            // 3 + SEQL
#define TTOK (BATCH*NPOS)   // 66304, divisible by 64 (1036 tiles)
#define HD 128
#define NHEAD 8
#define FF 512
#define DEPTH 4
#define CVOC 50001

typedef unsigned short u16;
typedef unsigned int u32;
typedef __bf16 bf16x8 __attribute__((ext_vector_type(8)));
typedef float f32x4 __attribute__((ext_vector_type(4)));

__device__ __forceinline__ u16 f2bf(float f) {
  u32 i = __float_as_uint(f);
  u32 r = (i + 0x7FFFu + ((i >> 16) & 1u)) >> 16;   // RNE
  return (u16)r;
}

// ---------------------------------------------------------------- transpose + downcast
// in (fp32): [D][K][N] -> out (bf16): [D][N][K]
__global__ void k_transpose(const float* __restrict__ in, u16* __restrict__ out,
                            int D, int K, int N) {
  int idx = blockIdx.x * 256 + threadIdx.x;
  int total = D * K * N;
  if (idx >= total) return;
  int k = idx % K; int rem = idx / K; int n = rem % N; int d = rem / N;
  out[idx] = f2bf(in[(d * K + k) * N + n]);
}

// ---------------------------------------------------------------- build x
// grid (NPOS, BATCH), 128 threads. x fp32 [TTOK][128]
__global__ __launch_bounds__(128)
void k_build(const int* __restrict__ item_seq, const int* __restrict__ act_seq,
             const int* __restrict__ tdiff,
             const int* __restrict__ ucv, const int* __restrict__ ucl, const float* __restrict__ unum,
             const int* __restrict__ icv, const int* __restrict__ icl, const float* __restrict__ inum,
             const float* __restrict__ item_t, const float* __restrict__ act_t,
             const float* __restrict__ time_t, const float* __restrict__ cat_t,
             const float* __restrict__ numW, const float* __restrict__ gtok,
             float* __restrict__ x) {
  int pos = blockIdx.x, b = blockIdx.y, h = threadIdx.x;
  float v;
  if (pos == 0) {
    v = gtok[h];
  } else if (pos <= 2) {
    const int* cv = (pos == 1) ? ucv : icv;
    const int* cl = (pos == 1) ? ucl : icl;
    const float* nm = (pos == 1) ? unum : inum;
    float acc = 0.f;
    for (int f = 0; f < 8; ++f) {
      float s = 0.f;
      for (int k = 0; k < 8; ++k) {
        int idx = cv[(b * 8 + f) * 8 + k];          // 0 beyond len; table row0==0
        s += cat_t[((size_t)f * CVOC + idx) * HD + h];
      }
      acc += s / (float)cl[b * 8 + f];
    }
    for (int f = 0; f < 4; ++f)
      for (int d = 0; d < 32; ++d)
        acc += nm[(b * 4 + f) * 32 + d] * numW[(f * 32 + d) * HD + h];
    v = acc * (1.f / 12.f);                          // /(NCAT+NNUM)
  } else {
    int l = pos - 3;
    v = item_t[(size_t)item_seq[b * SEQL + l] * HD + h]
      + act_t[(size_t)act_seq[b * SEQL + l] * HD + h]
      + time_t[(size_t)tdiff[b * SEQL + l] * HD + h];
  }
  x[((size_t)b * NPOS + pos) * HD + h] = v;
}

// ---------------------------------------------------------------- layernorm
// grid TTOK/4, 256 threads: one wave per token, 2 elems/lane. out bf16.
__global__ __launch_bounds__(256)
void k_ln(const float* __restrict__ x, const float* __restrict__ g,
          const float* __restrict__ be, u16* __restrict__ out) {
  int t = blockIdx.x * 4 + (threadIdx.x >> 6);
  int lane = threadIdx.x & 63;
  const float* xr = x + (size_t)t * HD;
  float a = xr[lane], c = xr[lane + 64];
  float s = a + c, s2 = a * a + c * c;
  #pragma unroll
  for (int o = 32; o; o >>= 1) { s += __shfl_xor(s, o); s2 += __shfl_xor(s2, o); }
  float mean = s * (1.f / HD);
  float var = s2 * (1.f / HD) - mean * mean;
  float rstd = rsqrtf(var + 1e-5f);
  out[(size_t)t * HD + lane]      = f2bf((a - mean) * rstd * g[lane] + be[lane]);
  out[(size_t)t * HD + lane + 64] = f2bf((c - mean) * rstd * g[lane + 64] + be[lane + 64]);
}

// ---------------------------------------------------------------- GEMM (MFMA)
// Y[T x N] = act(X[T x K] @ W[K x N] + bias); W given transposed+bf16 WT[N][K].
// tile 64x64, 4 waves x 16 rows. ACT: 0=none, 1=exact gelu. RESID: += into fp32.
template <int ACT, bool RESID>
__global__ __launch_bounds__(256)
void k_gemm(const u16* __restrict__ X, const u16* __restrict__ WT,
            const float* __restrict__ bias, void* __restrict__ outp,
            int K, int N) {
  __shared__ __align__(16) u16 lA[64 * 40];
  __shared__ __align__(16) u16 lB[64 * 40];
  const int tid = threadIdx.x;
  const int wave = tid >> 6, lane = tid & 63;
  const int row0 = blockIdx.x * 64;
  const int n0 = blockIdx.y * 64;
  const int srow = tid >> 2, scg = (tid & 3) * 8;
  const int fr = lane & 15, kg = (lane >> 4) * 8;
  f32x4 acc[4] = {};
  for (int k0 = 0; k0 < K; k0 += 32) {
    __syncthreads();
    *(uint4*)&lA[srow * 40 + scg] = *(const uint4*)&X[(size_t)(row0 + srow) * K + k0 + scg];
    *(uint4*)&lB[srow * 40 + scg] = *(const uint4*)&WT[(size_t)(n0 + srow) * K + k0 + scg];
    __syncthreads();
    bf16x8 afrag = *(const bf16x8*)&lA[(wave * 16 + fr) * 40 + kg];
    #pragma unroll
    for (int c = 0; c < 4; ++c) {
      bf16x8 bfrag = *(const bf16x8*)&lB[(c * 16 + fr) * 40 + kg];
      acc[c] = __builtin_amdgcn_mfma_f32_16x16x32_bf16(afrag, bfrag, acc[c], 0, 0, 0);
    }
  }
  const int rg = (lane >> 4) * 4;
  #pragma unroll
  for (int c = 0; c < 4; ++c) {
    int col = n0 + c * 16 + fr;
    float bv = bias[col];
    #pragma unroll
    for (int j = 0; j < 4; ++j) {
      int row = row0 + wave * 16 + rg + j;
      float v = acc[c][j] + bv;
      if (ACT == 1) v = 0.5f * v * (1.f + erff(v * 0.70710678118654752f));
      if (RESID) ((float*)outp)[(size_t)row * N + col] += v;
      else ((u16*)outp)[(size_t)row * N + col] = f2bf(v);
    }
  }
}

// ---------------------------------------------------------------- attention (MFMA flash)
// grid (NHEAD, BATCH), 256 threads = 4 waves. qkv: [T][384] bf16, cols s*128+h*16+i.
// Per wave: q-tiles of 16 rows. S^T = mfma(Kfrag, Qfrag) 16x16x32 (d padded 16->32).
// S^T D-layout: q = lane&15, k = (lane>>4)*4 + r. Softmax = column reduce (shfl 16,32).
// O^T = mfma(Vt-frag, Pt-frag, acc): Vt = V transposed in LDS; Pt built via 8 shfl.
// O^T D-layout: q = lane&15, d = (lane>>4)*4 + r -> rescale factors need NO shuffle.
#define KSTR 40    // K LDS row stride (u16): 80 B, 16B-aligned, bank-uniform b128
#define VSTR 280   // Vt LDS row stride (u16): 560 B, 16B-aligned, bank-uniform b128
__global__ __launch_bounds__(256)
void k_attn(const u16* __restrict__ qkv, const int* __restrict__ mask,
            u16* __restrict__ out) {
  int h = blockIdx.x, b = blockIdx.y;
  __shared__ __align__(16) u16 Ks[272 * KSTR];
  __shared__ __align__(16) u16 Vt[16 * VSTR];
  __shared__ int part[4];
  const int tid = threadIdx.x;
  // valid-prefix length
  int mv = (mask[b * SEQL + tid] != 0) ? 1 : 0;
  #pragma unroll
  for (int o = 32; o; o >>= 1) mv += __shfl_xor(mv, o);
  if ((tid & 63) == 0) part[tid >> 6] = mv;
  // stage K rows and V transposed
  {
    int half = tid & 1, i0 = half * 8;
    for (int r = tid >> 1; r < NPOS; r += 128) {
      const u16* src = &qkv[((size_t)(b * NPOS + r)) * 384 + h * 16 + 128 + i0];
      *(uint4*)&Ks[r * KSTR + i0] = *(const uint4*)src;
      uint4 vv = *(const uint4*)&src[128];
      u16 tmp[8]; *(uint4*)tmp = vv;
      #pragma unroll
      for (int j = 0; j < 8; ++j) Vt[(i0 + j) * VSTR + r] = tmp[j];
    }
    for (int r = NPOS + (tid >> 1); r < 272; r += 128) {
      *(uint4*)&Ks[r * KSTR + i0] = make_uint4(0, 0, 0, 0);
      #pragma unroll
      for (int j = 0; j < 8; ++j) Vt[(i0 + j) * VSTR + r] = 0;
    }
  }
  __syncthreads();
  const int nvalid = part[0] + part[1] + part[2] + part[3] + 3;
  const int ktiles = (nvalid + 15) >> 4;
  const int wave = tid >> 6, lane = tid & 63;
  const int g = lane >> 4, q16 = lane & 15;
  const f32x4 zf = {};
  for (int qt = wave; qt < 17; qt += 4) {
    int q0 = qt * 16;
    bf16x8 qf = {};
    if (g < 2) {
      int qrow = q0 + q16; if (qrow > NPOS - 1) qrow = NPOS - 1;
      qf = *(const bf16x8*)&qkv[((size_t)(b * NPOS + qrow)) * 384 + h * 16 + g * 8];
    }
    float m = -1e30f, l = 0.f;
    f32x4 acc = {};                 // O^T: q=q16, d=g*4+r
    for (int kt = 0; kt < ktiles; ++kt) {
      bf16x8 kf = {};
      if (g < 2) kf = *(const bf16x8*)&Ks[(kt * 16 + q16) * KSTR + g * 8];
      f32x4 s4 = __builtin_amdgcn_mfma_f32_16x16x32_bf16(kf, qf, zf, 0, 0, 0);
      float s[4];
      #pragma unroll
      for (int r = 0; r < 4; ++r) {
        int kg = kt * 16 + g * 4 + r;
        float v = s4[r] * 0.25f;    // SCALE = (128/8)^-0.5
        s[r] = (kg < nvalid) ? v : -1e30f;
      }
      float tmax = fmaxf(fmaxf(s[0], s[1]), fmaxf(s[2], s[3]));
      tmax = fmaxf(tmax, __shfl_xor(tmax, 16));
      tmax = fmaxf(tmax, __shfl_xor(tmax, 32));
      float mnew = fmaxf(m, tmax);
      float fac = __expf(m - mnew);
      float p[4];
      #pragma unroll
      for (int r = 0; r < 4; ++r) p[r] = __expf(s[r] - mnew);
      float tsum = p[0] + p[1] + p[2] + p[3];
      tsum += __shfl_xor(tsum, 16);
      tsum += __shfl_xor(tsum, 32);
      l = l * fac + tsum;
      m = mnew;
      #pragma unroll
      for (int r = 0; r < 4; ++r) acc[r] *= fac;
      // build P^T frag: lane needs P[q16][kk=g*8+j] (kk<16 real, else 0)
      union { u32 u[4]; bf16x8 v; } pu;
      #pragma unroll
      for (int jj = 0; jj < 8; ++jj) {
        int kk = g * 8 + jj;
        int srcl = ((kk & 15) >> 2) * 16 + q16;
        float pv = __shfl(p[jj & 3], srcl);
        u16 pb = (kk < 16) ? f2bf(pv) : (u16)0;
        if ((jj & 1) == 0) pu.u[jj >> 1] = pb; else pu.u[jj >> 1] |= ((u32)pb) << 16;
      }
      bf16x8 vf = {};
      if (g < 2) vf = *(const bf16x8*)&Vt[q16 * VSTR + kt * 16 + g * 8];
      acc = __builtin_amdgcn_mfma_f32_16x16x32_bf16(vf, pu.v, acc, 0, 0, 0);
    }
    float linv = 1.f / l;
    int qrow = q0 + q16;
    if (qrow < NPOS) {
      u16* op = &out[((size_t)(b * NPOS + qrow)) * HD + h * 16];
      #pragma unroll
      for (int r = 0; r < 4; ++r) op[g * 4 + r] = f2bf(acc[r] * linv);
    }
  }
}

// ---------------------------------------------------------------- head
// grid BATCH, 128 threads. logits[b] then embed[b][h], fp32 out.
__global__ __launch_bounds__(128)
void k_head(const float* __restrict__ x, const float* __restrict__ bw,
            const float* __restrict__ bb, const float* __restrict__ cw,
            const float* __restrict__ cb, float* __restrict__ dout) {
  int b = blockIdx.x, n = threadIdx.x;
  __shared__ float lat[HD];
  __shared__ float redp[2], redss[2];
  float lv = x[((size_t)b * NPOS) * HD + n];
  lat[n] = lv;
  __syncthreads();
  float t = 0.f;
  for (int k = 0; k < HD; ++k) t += lat[k] * bw[k * HD + n];
  t += bb[n];
  t = fmaxf(t, 0.f);
  float p = t * cw[n];
  float ss = lv * lv;
  #pragma unroll
  for (int o = 32; o; o >>= 1) { p += __shfl_xor(p, o); ss += __shfl_xor(ss, o); }
  if ((n & 63) == 0) { redp[n >> 6] = p; redss[n >> 6] = ss; }
  __syncthreads();
  float psum = redp[0] + redp[1];
  float ssum = redss[0] + redss[1];
  if (n == 0) dout[b] = psum + cb[0];
  float nrm = fmaxf(sqrtf(ssum), 1e-12f);
  dout[256 + (size_t)b * HD + n] = lv / nrm;
}

// ---------------------------------------------------------------- launch
extern "C" void kernel_launch(void* const* d_in, const int* in_sizes, int n_in,
                              void* d_out, int out_size, void* d_ws, size_t ws_size,
                              hipStream_t stream) {
  const int* item_seq = (const int*)d_in[0];
  const int* action_seq = (const int*)d_in[1];
  const int* time_diff = (const int*)d_in[2];
  const int* mask = (const int*)d_in[3];
  const int* u_cv = (const int*)d_in[4];
  const int* u_cl = (const int*)d_in[5];
  const float* u_num = (const float*)d_in[6];
  const int* i_cv = (const int*)d_in[7];
  const int* i_cl = (const int*)d_in[8];
  const float* i_num = (const float*)d_in[9];
  const float* item_t = (const float*)d_in[10];
  const float* act_t = (const float*)d_in[11];
  const float* time_t = (const float*)d_in[12];
  const float* cat_t = (const float*)d_in[13];
  const float* num_W = (const float*)d_in[14];
  const float* gtok = (const float*)d_in[15];
  const float* ln1_g = (const float*)d_in[16];
  const float* ln1_b = (const float*)d_in[17];
  const float* qkv_w = (const float*)d_in[18];
  const float* qkv_b = (const float*)d_in[19];
  const float* out_w = (const float*)d_in[20];
  const float* out_b = (const float*)d_in[21];
  const float* w1 = (const float*)d_in[22];
  const float* b1 = (const float*)d_in[23];
  const float* w2 = (const float*)d_in[24];
  const float* b2 = (const float*)d_in[25];
  const float* ln2_g = (const float*)d_in[26];
  const float* ln2_b = (const float*)d_in[27];
  const float* bott_w = (const float*)d_in[28];
  const float* bott_b = (const float*)d_in[29];
  const float* cls_w = (const float*)d_in[30];
  const float* cls_b = (const float*)d_in[31];

  // workspace layout (bytes)
  const size_t off_x   = 0;                    // TTOK*128 f32  = 33,947,648
  const size_t off_src = 33947648;             // TTOK*128 bf16 = 16,973,824 (src / attnout)
  const size_t off_big = 50921472;             // TTOK*512 bf16 = 67,895,296 (qkv / h1)
  const size_t off_wT  = 118816768;            // 786,432 elems bf16
  const size_t need    = 120389632;
  if (ws_size < need) {
    fprintf(stderr, "kernel_launch: ws_size %zu < needed %zu\n", ws_size, need);
    return;
  }
  char* ws = (char*)d_ws;
  float* x   = (float*)(ws + off_x);
  u16* src   = (u16*)(ws + off_src);
  u16* big   = (u16*)(ws + off_big);
  u16* wT    = (u16*)(ws + off_wT);
  u16* qkvT  = wT;                 // [4][384][128]
  u16* outT  = wT + 196608;        // [4][128][128]
  u16* w1T   = wT + 262144;        // [4][512][128]
  u16* w2T   = wT + 524288;        // [4][128][512]

  k_transpose<<<(4 * 128 * 384 + 255) / 256, 256, 0, stream>>>(qkv_w, qkvT, 4, 128, 384);
  k_transpose<<<(4 * 128 * 128 + 255) / 256, 256, 0, stream>>>(out_w, outT, 4, 128, 128);
  k_transpose<<<(4 * 128 * 512 + 255) / 256, 256, 0, stream>>>(w1, w1T, 4, 128, 512);
  k_transpose<<<(4 * 512 * 128 + 255) / 256, 256, 0, stream>>>(w2, w2T, 4, 512, 128);

  k_build<<<dim3(NPOS, BATCH), 128, 0, stream>>>(
      item_seq, action_seq, time_diff, u_cv, u_cl, u_num, i_cv, i_cl, i_num,
      item_t, act_t, time_t, cat_t, num_W, gtok, x);

  const int rt = TTOK / 64;  // 1036
  for (int dd = 0; dd < DEPTH; ++dd) {
    k_ln<<<TTOK / 4, 256, 0, stream>>>(x, ln1_g + dd * HD, ln1_b + dd * HD, src);
    k_gemm<0, false><<<dim3(rt, 6), 256, 0, stream>>>(src, qkvT + dd * 49152, qkv_b + dd * 384, big, 128, 384);
    k_attn<<<dim3(NHEAD, BATCH), 256, 0, stream>>>(big, mask, src);
    k_gemm<0, true><<<dim3(rt, 2), 256, 0, stream>>>(src, outT + dd * 16384, out_b + dd * HD, x, 128, 128);
    k_ln<<<TTOK / 4, 256, 0, stream>>>(x, ln2_g + dd * HD, ln2_b + dd * HD, src);
    k_gemm<1, false><<<dim3(rt, 8), 256, 0, stream>>>(src, w1T + dd * 65536, b1 + dd * FF, big, 128, 512);
    k_gemm<0, true><<<dim3(rt, 2), 256, 0, stream>>>(big, w2T + dd * 65536, b2 + dd * HD, x, 512, 128);
  }

  k_head<<<BATCH, 128, 0, stream>>>(x, bott_w, bott_b, cls_w, cls_b, (float*)d_out);
}

// Round 4
// 1064.994 us; speedup vs baseline: 1.7678x; 1.0411x over previous
//
#include <hip/hip_runtime.h>
#include <cstdio>

// Problem constants
#define BATCH 256
#define SEQL 256
#define NPOS 259            // 3 + SEQL
#define TTOK (BATCH*NPOS)   // 66304 = 518 * 128
#define HD 128
#define NHEAD 8
#define FF 512
#define DEPTH 4
#define CVOC 50001

typedef unsigned short u16;
typedef unsigned int u32;
typedef __bf16 bf16x8 __attribute__((ext_vector_type(8)));
typedef float f32x4 __attribute__((ext_vector_type(4)));

typedef const __attribute__((address_space(1))) u32 gas_u32;
typedef __attribute__((address_space(3))) u32 las_u32;
#define GLOAD16(gptr, lptr) \
  __builtin_amdgcn_global_load_lds((gas_u32*)(gptr), (las_u32*)(lptr), 16, 0, 0)

__device__ __forceinline__ u16 f2bf(float f) {
  u32 i = __float_as_uint(f);
  u32 r = (i + 0x7FFFu + ((i >> 16) & 1u)) >> 16;   // RNE
  return (u16)r;
}

// ---------------------------------------------------------------- transpose + downcast
// in (fp32): [D][K][N] -> out (bf16): [D][N][K]
__global__ void k_transpose(const float* __restrict__ in, u16* __restrict__ out,
                            int D, int K, int N) {
  int idx = blockIdx.x * 256 + threadIdx.x;
  int total = D * K * N;
  if (idx >= total) return;
  int k = idx % K; int rem = idx / K; int n = rem % N; int d = rem / N;
  out[idx] = f2bf(in[(d * K + k) * N + n]);
}

// ---------------------------------------------------------------- build x
// grid (NPOS, BATCH), 128 threads. x fp32 [TTOK][128]
__global__ __launch_bounds__(128)
void k_build(const int* __restrict__ item_seq, const int* __restrict__ act_seq,
             const int* __restrict__ tdiff,
             const int* __restrict__ ucv, const int* __restrict__ ucl, const float* __restrict__ unum,
             const int* __restrict__ icv, const int* __restrict__ icl, const float* __restrict__ inum,
             const float* __restrict__ item_t, const float* __restrict__ act_t,
             const float* __restrict__ time_t, const float* __restrict__ cat_t,
             const float* __restrict__ numW, const float* __restrict__ gtok,
             float* __restrict__ x) {
  int pos = blockIdx.x, b = blockIdx.y, h = threadIdx.x;
  float v;
  if (pos == 0) {
    v = gtok[h];
  } else if (pos <= 2) {
    const int* cv = (pos == 1) ? ucv : icv;
    const int* cl = (pos == 1) ? ucl : icl;
    const float* nm = (pos == 1) ? unum : inum;
    float acc = 0.f;
    for (int f = 0; f < 8; ++f) {
      float s = 0.f;
      for (int k = 0; k < 8; ++k) {
        int idx = cv[(b * 8 + f) * 8 + k];          // 0 beyond len; table row0==0
        s += cat_t[((size_t)f * CVOC + idx) * HD + h];
      }
      acc += s / (float)cl[b * 8 + f];
    }
    for (int f = 0; f < 4; ++f)
      for (int d = 0; d < 32; ++d)
        acc += nm[(b * 4 + f) * 32 + d] * numW[(f * 32 + d) * HD + h];
    v = acc * (1.f / 12.f);                          // /(NCAT+NNUM)
  } else {
    int l = pos - 3;
    v = item_t[(size_t)item_seq[b * SEQL + l] * HD + h]
      + act_t[(size_t)act_seq[b * SEQL + l] * HD + h]
      + time_t[(size_t)tdiff[b * SEQL + l] * HD + h];
  }
  x[((size_t)b * NPOS + pos) * HD + h] = v;
}

// ---------------------------------------------------------------- layernorm
// grid TTOK/4, 256 threads: one wave per token, 2 elems/lane. out bf16.
__global__ __launch_bounds__(256)
void k_ln(const float* __restrict__ x, const float* __restrict__ g,
          const float* __restrict__ be, u16* __restrict__ out) {
  int t = blockIdx.x * 4 + (threadIdx.x >> 6);
  int lane = threadIdx.x & 63;
  const float* xr = x + (size_t)t * HD;
  float a = xr[lane], c = xr[lane + 64];
  float s = a + c, s2 = a * a + c * c;
  #pragma unroll
  for (int o = 32; o; o >>= 1) { s += __shfl_xor(s, o); s2 += __shfl_xor(s2, o); }
  float mean = s * (1.f / HD);
  float var = s2 * (1.f / HD) - mean * mean;
  float rstd = rsqrtf(var + 1e-5f);
  out[(size_t)t * HD + lane]      = f2bf((a - mean) * rstd * g[lane] + be[lane]);
  out[(size_t)t * HD + lane + 64] = f2bf((c - mean) * rstd * g[lane + 64] + be[lane + 64]);
}

// ---------------------------------------------------------------- GEMM (MFMA, m97 structure)
// Y[T x N] = act(X[T x K] + bias); WT[N][K] bf16. Tile 128x128, 4 waves 2x2,
// each wave 64x64 = 4x4 fragments. BK=32. global_load_lds(16B) staging with
// XOR-swizzled LDS (pre-swizzled global source + swizzled ds_read).
// ACT: 0=none, 1=exact gelu. RESID: += into fp32 outp.
template <int ACT, bool RESID>
__global__ __launch_bounds__(256)
void k_gemm(const u16* __restrict__ X, const u16* __restrict__ WT,
            const float* __restrict__ bias, void* __restrict__ outp,
            int K, int N) {
  __shared__ __align__(16) u16 lA[128 * 32];
  __shared__ __align__(16) u16 lB[128 * 32];
  const int tid = threadIdx.x;
  const int wave = tid >> 6, lane = tid & 63;
  const int row0 = blockIdx.x * 128;
  const int n0 = blockIdx.y * 128;
  const int wr = (wave >> 1) * 64, wc = (wave & 1) * 64;
  // staging: lane writes LDS slot (r = wave*16 + lane/4, c16_phys = lane&3);
  // source column-segment pre-swizzled so phys slot (r,p) holds logical (r, p^((r>>1)&3)).
  const int sr = lane >> 2;
  const int sc = ((lane & 3) ^ ((lane >> 3) & 3)) << 3;   // u16 units
  const u16* gA0 = X  + (size_t)(row0 + wave * 16 + sr) * K + sc;
  const u16* gA1 = X  + (size_t)(row0 + 64 + wave * 16 + sr) * K + sc;
  const u16* gB0 = WT + (size_t)(n0 + wave * 16 + sr) * K + sc;
  const u16* gB1 = WT + (size_t)(n0 + 64 + wave * 16 + sr) * K + sc;
  u16* lA0 = &lA[wave * 512];          // wave-uniform bases (lane*16B appended by HW)
  u16* lA1 = &lA[2048 + wave * 512];
  u16* lB0 = &lB[wave * 512];
  u16* lB1 = &lB[2048 + wave * 512];
  // fragment read: logical (r = blk + q, c16 = cg) at phys c16 = cg ^ ((q>>1)&3)
  const int q = lane & 15;
  const int cg = lane >> 4;
  const int rdoff = ((cg ^ ((q >> 1) & 3)) << 3);
  f32x4 acc[4][4] = {};
  for (int k0 = 0; k0 < K; k0 += 32) {
    __syncthreads();
    GLOAD16(gA0 + k0, lA0);
    GLOAD16(gA1 + k0, lA1);
    GLOAD16(gB0 + k0, lB0);
    GLOAD16(gB1 + k0, lB1);
    __syncthreads();            // compiler drains vmcnt+lgkmcnt here
    bf16x8 af[4], bf[4];
    #pragma unroll
    for (int i = 0; i < 4; ++i)
      af[i] = *(const bf16x8*)&lA[(wr + i * 16 + q) * 32 + rdoff];
    #pragma unroll
    for (int j = 0; j < 4; ++j)
      bf[j] = *(const bf16x8*)&lB[(wc + j * 16 + q) * 32 + rdoff];
    #pragma unroll
    for (int i = 0; i < 4; ++i)
      #pragma unroll
      for (int j = 0; j < 4; ++j)
        acc[i][j] = __builtin_amdgcn_mfma_f32_16x16x32_bf16(af[i], bf[j], acc[i][j], 0, 0, 0);
  }
  const int rg = cg * 4;
  #pragma unroll
  for (int i = 0; i < 4; ++i) {
    #pragma unroll
    for (int j = 0; j < 4; ++j) {
      int col = n0 + wc + j * 16 + q;
      float bv = bias[col];
      #pragma unroll
      for (int jj = 0; jj < 4; ++jj) {
        int row = row0 + wr + i * 16 + rg + jj;
        float v = acc[i][j][jj] + bv;
        if (ACT == 1) v = 0.5f * v * (1.f + erff(v * 0.70710678118654752f));
        if (RESID) ((float*)outp)[(size_t)row * N + col] += v;
        else ((u16*)outp)[(size_t)row * N + col] = f2bf(v);
      }
    }
  }
}

// ---------------------------------------------------------------- attention (MFMA flash)
// grid (NHEAD, BATCH), 256 threads = 4 waves. qkv: [T][384] bf16, cols s*128+h*16+i.
#define KSTR 40    // K LDS row stride (u16)
#define VSTR 280   // Vt LDS row stride (u16)
__global__ __launch_bounds__(256)
void k_attn(const u16* __restrict__ qkv, const int* __restrict__ mask,
            u16* __restrict__ out) {
  int h = blockIdx.x, b = blockIdx.y;
  __shared__ __align__(16) u16 Ks[272 * KSTR];
  __shared__ __align__(16) u16 Vt[16 * VSTR];
  __shared__ int part[4];
  const int tid = threadIdx.x;
  int mv = (mask[b * SEQL + tid] != 0) ? 1 : 0;
  #pragma unroll
  for (int o = 32; o; o >>= 1) mv += __shfl_xor(mv, o);
  if ((tid & 63) == 0) part[tid >> 6] = mv;
  {
    int half = tid & 1, i0 = half * 8;
    for (int r = tid >> 1; r < NPOS; r += 128) {
      const u16* src = &qkv[((size_t)(b * NPOS + r)) * 384 + h * 16 + 128 + i0];
      *(uint4*)&Ks[r * KSTR + i0] = *(const uint4*)src;
      uint4 vv = *(const uint4*)&src[128];
      u16 tmp[8]; *(uint4*)tmp = vv;
      #pragma unroll
      for (int j = 0; j < 8; ++j) Vt[(i0 + j) * VSTR + r] = tmp[j];
    }
    for (int r = NPOS + (tid >> 1); r < 272; r += 128) {
      *(uint4*)&Ks[r * KSTR + i0] = make_uint4(0, 0, 0, 0);
      #pragma unroll
      for (int j = 0; j < 8; ++j) Vt[(i0 + j) * VSTR + r] = 0;
    }
  }
  __syncthreads();
  const int nvalid = part[0] + part[1] + part[2] + part[3] + 3;
  const int ktiles = (nvalid + 15) >> 4;
  const int wave = tid >> 6, lane = tid & 63;
  const int g = lane >> 4, q16 = lane & 15;
  const f32x4 zf = {};
  for (int qt = wave; qt < 17; qt += 4) {
    int q0 = qt * 16;
    bf16x8 qf = {};
    if (g < 2) {
      int qrow = q0 + q16; if (qrow > NPOS - 1) qrow = NPOS - 1;
      qf = *(const bf16x8*)&qkv[((size_t)(b * NPOS + qrow)) * 384 + h * 16 + g * 8];
    }
    float m = -1e30f, l = 0.f;
    f32x4 acc = {};
    for (int kt = 0; kt < ktiles; ++kt) {
      bf16x8 kf = {};
      if (g < 2) kf = *(const bf16x8*)&Ks[(kt * 16 + q16) * KSTR + g * 8];
      f32x4 s4 = __builtin_amdgcn_mfma_f32_16x16x32_bf16(kf, qf, zf, 0, 0, 0);
      float s[4];
      #pragma unroll
      for (int r = 0; r < 4; ++r) {
        int kg = kt * 16 + g * 4 + r;
        float v = s4[r] * 0.25f;    // SCALE
        s[r] = (kg < nvalid) ? v : -1e30f;
      }
      float tmax = fmaxf(fmaxf(s[0], s[1]), fmaxf(s[2], s[3]));
      tmax = fmaxf(tmax, __shfl_xor(tmax, 16));
      tmax = fmaxf(tmax, __shfl_xor(tmax, 32));
      float mnew = fmaxf(m, tmax);
      float fac = __expf(m - mnew);
      float p[4];
      #pragma unroll
      for (int r = 0; r < 4; ++r) p[r] = __expf(s[r] - mnew);
      float tsum = p[0] + p[1] + p[2] + p[3];
      tsum += __shfl_xor(tsum, 16);
      tsum += __shfl_xor(tsum, 32);
      l = l * fac + tsum;
      m = mnew;
      #pragma unroll
      for (int r = 0; r < 4; ++r) acc[r] *= fac;
      union { u32 u[4]; bf16x8 v; } pu;
      #pragma unroll
      for (int jj = 0; jj < 8; ++jj) {
        int kk = g * 8 + jj;
        int srcl = ((kk & 15) >> 2) * 16 + q16;
        float pv = __shfl(p[jj & 3], srcl);
        u16 pb = (kk < 16) ? f2bf(pv) : (u16)0;
        if ((jj & 1) == 0) pu.u[jj >> 1] = pb; else pu.u[jj >> 1] |= ((u32)pb) << 16;
      }
      bf16x8 vf = {};
      if (g < 2) vf = *(const bf16x8*)&Vt[q16 * VSTR + kt * 16 + g * 8];
      acc = __builtin_amdgcn_mfma_f32_16x16x32_bf16(vf, pu.v, acc, 0, 0, 0);
    }
    float linv = 1.f / l;
    int qrow = q0 + q16;
    if (qrow < NPOS) {
      u16* op = &out[((size_t)(b * NPOS + qrow)) * HD + h * 16];
      #pragma unroll
      for (int r = 0; r < 4; ++r) op[g * 4 + r] = f2bf(acc[r] * linv);
    }
  }
}

// ---------------------------------------------------------------- head
__global__ __launch_bounds__(128)
void k_head(const float* __restrict__ x, const float* __restrict__ bw,
            const float* __restrict__ bb, const float* __restrict__ cw,
            const float* __restrict__ cb, float* __restrict__ dout) {
  int b = blockIdx.x, n = threadIdx.x;
  __shared__ float lat[HD];
  __shared__ float redp[2], redss[2];
  float lv = x[((size_t)b * NPOS) * HD + n];
  lat[n] = lv;
  __syncthreads();
  float t = 0.f;
  for (int k = 0; k < HD; ++k) t += lat[k] * bw[k * HD + n];
  t += bb[n];
  t = fmaxf(t, 0.f);
  float p = t * cw[n];
  float ss = lv * lv;
  #pragma unroll
  for (int o = 32; o; o >>= 1) { p += __shfl_xor(p, o); ss += __shfl_xor(ss, o); }
  if ((n & 63) == 0) { redp[n >> 6] = p; redss[n >> 6] = ss; }
  __syncthreads();
  float psum = redp[0] + redp[1];
  float ssum = redss[0] + redss[1];
  if (n == 0) dout[b] = psum + cb[0];
  float nrm = fmaxf(sqrtf(ssum), 1e-12f);
  dout[256 + (size_t)b * HD + n] = lv / nrm;
}

// ---------------------------------------------------------------- launch
extern "C" void kernel_launch(void* const* d_in, const int* in_sizes, int n_in,
                              void* d_out, int out_size, void* d_ws, size_t ws_size,
                              hipStream_t stream) {
  const int* item_seq = (const int*)d_in[0];
  const int* action_seq = (const int*)d_in[1];
  const int* time_diff = (const int*)d_in[2];
  const int* mask = (const int*)d_in[3];
  const int* u_cv = (const int*)d_in[4];
  const int* u_cl = (const int*)d_in[5];
  const float* u_num = (const float*)d_in[6];
  const int* i_cv = (const int*)d_in[7];
  const int* i_cl = (const int*)d_in[8];
  const float* i_num = (const float*)d_in[9];
  const float* item_t = (const float*)d_in[10];
  const float* act_t = (const float*)d_in[11];
  const float* time_t = (const float*)d_in[12];
  const float* cat_t = (const float*)d_in[13];
  const float* num_W = (const float*)d_in[14];
  const float* gtok = (const float*)d_in[15];
  const float* ln1_g = (const float*)d_in[16];
  const float* ln1_b = (const float*)d_in[17];
  const float* qkv_w = (const float*)d_in[18];
  const float* qkv_b = (const float*)d_in[19];
  const float* out_w = (const float*)d_in[20];
  const float* out_b = (const float*)d_in[21];
  const float* w1 = (const float*)d_in[22];
  const float* b1 = (const float*)d_in[23];
  const float* w2 = (const float*)d_in[24];
  const float* b2 = (const float*)d_in[25];
  const float* ln2_g = (const float*)d_in[26];
  const float* ln2_b = (const float*)d_in[27];
  const float* bott_w = (const float*)d_in[28];
  const float* bott_b = (const float*)d_in[29];
  const float* cls_w = (const float*)d_in[30];
  const float* cls_b = (const float*)d_in[31];

  // workspace layout (bytes)
  const size_t off_x   = 0;                    // TTOK*128 f32  = 33,947,648
  const size_t off_src = 33947648;             // TTOK*128 bf16 = 16,973,824
  const size_t off_big = 50921472;             // TTOK*512 bf16 = 67,895,296
  const size_t off_wT  = 118816768;            // 786,432 elems bf16
  const size_t need    = 120389632;
  if (ws_size < need) {
    fprintf(stderr, "kernel_launch: ws_size %zu < needed %zu\n", ws_size, need);
    return;
  }
  char* ws = (char*)d_ws;
  float* x   = (float*)(ws + off_x);
  u16* src   = (u16*)(ws + off_src);
  u16* big   = (u16*)(ws + off_big);
  u16* wT    = (u16*)(ws + off_wT);
  u16* qkvT  = wT;                 // [4][384][128]
  u16* outT  = wT + 196608;        // [4][128][128]
  u16* w1T   = wT + 262144;        // [4][512][128]
  u16* w2T   = wT + 524288;        // [4][128][512]

  k_transpose<<<(4 * 128 * 384 + 255) / 256, 256, 0, stream>>>(qkv_w, qkvT, 4, 128, 384);
  k_transpose<<<(4 * 128 * 128 + 255) / 256, 256, 0, stream>>>(out_w, outT, 4, 128, 128);
  k_transpose<<<(4 * 128 * 512 + 255) / 256, 256, 0, stream>>>(w1, w1T, 4, 128, 512);
  k_transpose<<<(4 * 512 * 128 + 255) / 256, 256, 0, stream>>>(w2, w2T, 4, 512, 128);

  k_build<<<dim3(NPOS, BATCH), 128, 0, stream>>>(
      item_seq, action_seq, time_diff, u_cv, u_cl, u_num, i_cv, i_cl, i_num,
      item_t, act_t, time_t, cat_t, num_W, gtok, x);

  const int rt = TTOK / 128;  // 518
  for (int dd = 0; dd < DEPTH; ++dd) {
    k_ln<<<TTOK / 4, 256, 0, stream>>>(x, ln1_g + dd * HD, ln1_b + dd * HD, src);
    k_gemm<0, false><<<dim3(rt, 3), 256, 0, stream>>>(src, qkvT + dd * 49152, qkv_b + dd * 384, big, 128, 384);
    k_attn<<<dim3(NHEAD, BATCH), 256, 0, stream>>>(big, mask, src);
    k_gemm<0, true><<<dim3(rt, 1), 256, 0, stream>>>(src, outT + dd * 16384, out_b + dd * HD, x, 128, 128);
    k_ln<<<TTOK / 4, 256, 0, stream>>>(x, ln2_g + dd * HD, ln2_b + dd * HD, src);
    k_gemm<1, false><<<dim3(rt, 4), 256, 0, stream>>>(src, w1T + dd * 65536, b1 + dd * FF, big, 128, 512);
    k_gemm<0, true><<<dim3(rt, 1), 256, 0, stream>>>(big, w2T + dd * 65536, b2 + dd * HD, x, 512, 128);
  }

  k_head<<<BATCH, 128, 0, stream>>>(x, bott_w, bott_b, cls_w, cls_b, (float*)d_out);
}

// Round 5
// 887.879 us; speedup vs baseline: 2.1204x; 1.1995x over previous
//
#include <hip/hip_runtime.h>
#include <cstdio>

// Problem constants
#define BATCH 256
#define SEQL 256
#define NPOS 259            // 3 + SEQL
#define TTOK (BATCH*NPOS)   // 66304 = 518 * 128
#define HD 128
#define NHEAD 8
#define FF 512
#define DEPTH 4
#define CVOC 50001

typedef unsigned short u16;
typedef unsigned int u32;
typedef __bf16 bf16x8 __attribute__((ext_vector_type(8)));
typedef float f32x4 __attribute__((ext_vector_type(4)));
typedef float f32x16 __attribute__((ext_vector_type(16)));

typedef const __attribute__((address_space(1))) u32 gas_u32;
typedef __attribute__((address_space(3))) u32 las_u32;
#define GLOAD16(gptr, lptr) \
  __builtin_amdgcn_global_load_lds((gas_u32*)(gptr), (las_u32*)(lptr), 16, 0, 0)

__device__ __forceinline__ u16 f2bf(float f) {
  u32 i = __float_as_uint(f);
  u32 r = (i + 0x7FFFu + ((i >> 16) & 1u)) >> 16;   // RNE
  return (u16)r;
}

// ---------------------------------------------------------------- transpose + downcast
// in (fp32): [D][K][N] -> out (bf16): [D][N][K]
__global__ void k_transpose(const float* __restrict__ in, u16* __restrict__ out,
                            int D, int K, int N) {
  int idx = blockIdx.x * 256 + threadIdx.x;
  int total = D * K * N;
  if (idx >= total) return;
  int k = idx % K; int rem = idx / K; int n = rem % N; int d = rem / N;
  out[idx] = f2bf(in[(d * K + k) * N + n]);
}

// ---------------------------------------------------------------- build x
__global__ __launch_bounds__(128)
void k_build(const int* __restrict__ item_seq, const int* __restrict__ act_seq,
             const int* __restrict__ tdiff,
             const int* __restrict__ ucv, const int* __restrict__ ucl, const float* __restrict__ unum,
             const int* __restrict__ icv, const int* __restrict__ icl, const float* __restrict__ inum,
             const float* __restrict__ item_t, const float* __restrict__ act_t,
             const float* __restrict__ time_t, const float* __restrict__ cat_t,
             const float* __restrict__ numW, const float* __restrict__ gtok,
             float* __restrict__ x) {
  int pos = blockIdx.x, b = blockIdx.y, h = threadIdx.x;
  float v;
  if (pos == 0) {
    v = gtok[h];
  } else if (pos <= 2) {
    const int* cv = (pos == 1) ? ucv : icv;
    const int* cl = (pos == 1) ? ucl : icl;
    const float* nm = (pos == 1) ? unum : inum;
    float acc = 0.f;
    for (int f = 0; f < 8; ++f) {
      float s = 0.f;
      for (int k = 0; k < 8; ++k) {
        int idx = cv[(b * 8 + f) * 8 + k];
        s += cat_t[((size_t)f * CVOC + idx) * HD + h];
      }
      acc += s / (float)cl[b * 8 + f];
    }
    for (int f = 0; f < 4; ++f)
      for (int d = 0; d < 32; ++d)
        acc += nm[(b * 4 + f) * 32 + d] * numW[(f * 32 + d) * HD + h];
    v = acc * (1.f / 12.f);
  } else {
    int l = pos - 3;
    v = item_t[(size_t)item_seq[b * SEQL + l] * HD + h]
      + act_t[(size_t)act_seq[b * SEQL + l] * HD + h]
      + time_t[(size_t)tdiff[b * SEQL + l] * HD + h];
  }
  x[((size_t)b * NPOS + pos) * HD + h] = v;
}

// ---------------------------------------------------------------- layernorm
__global__ __launch_bounds__(256)
void k_ln(const float* __restrict__ x, const float* __restrict__ g,
          const float* __restrict__ be, u16* __restrict__ out) {
  int t = blockIdx.x * 4 + (threadIdx.x >> 6);
  int lane = threadIdx.x & 63;
  const float* xr = x + (size_t)t * HD;
  float a = xr[lane], c = xr[lane + 64];
  float s = a + c, s2 = a * a + c * c;
  #pragma unroll
  for (int o = 32; o; o >>= 1) { s += __shfl_xor(s, o); s2 += __shfl_xor(s2, o); }
  float mean = s * (1.f / HD);
  float var = s2 * (1.f / HD) - mean * mean;
  float rstd = rsqrtf(var + 1e-5f);
  out[(size_t)t * HD + lane]      = f2bf((a - mean) * rstd * g[lane] + be[lane]);
  out[(size_t)t * HD + lane + 64] = f2bf((c - mean) * rstd * g[lane + 64] + be[lane + 64]);
}

// ---------------------------------------------------------------- GEMM (MFMA, m97 structure)
// QS: multiply cols<128 by 0.25 (folds attention SCALE into the q output).
template <int ACT, bool RESID, bool QS>
__global__ __launch_bounds__(256)
void k_gemm(const u16* __restrict__ X, const u16* __restrict__ WT,
            const float* __restrict__ bias, void* __restrict__ outp,
            int K, int N) {
  __shared__ __align__(16) u16 lA[128 * 32];
  __shared__ __align__(16) u16 lB[128 * 32];
  const int tid = threadIdx.x;
  const int wave = tid >> 6, lane = tid & 63;
  const int row0 = blockIdx.x * 128;
  const int n0 = blockIdx.y * 128;
  const int wr = (wave >> 1) * 64, wc = (wave & 1) * 64;
  const int sr = lane >> 2;
  const int sc = ((lane & 3) ^ ((lane >> 3) & 3)) << 3;
  const u16* gA0 = X  + (size_t)(row0 + wave * 16 + sr) * K + sc;
  const u16* gA1 = X  + (size_t)(row0 + 64 + wave * 16 + sr) * K + sc;
  const u16* gB0 = WT + (size_t)(n0 + wave * 16 + sr) * K + sc;
  const u16* gB1 = WT + (size_t)(n0 + 64 + wave * 16 + sr) * K + sc;
  u16* lA0 = &lA[wave * 512];
  u16* lA1 = &lA[2048 + wave * 512];
  u16* lB0 = &lB[wave * 512];
  u16* lB1 = &lB[2048 + wave * 512];
  const int q = lane & 15;
  const int cg = lane >> 4;
  const int rdoff = ((cg ^ ((q >> 1) & 3)) << 3);
  f32x4 acc[4][4] = {};
  for (int k0 = 0; k0 < K; k0 += 32) {
    __syncthreads();
    GLOAD16(gA0 + k0, lA0);
    GLOAD16(gA1 + k0, lA1);
    GLOAD16(gB0 + k0, lB0);
    GLOAD16(gB1 + k0, lB1);
    __syncthreads();
    bf16x8 af[4], bf[4];
    #pragma unroll
    for (int i = 0; i < 4; ++i)
      af[i] = *(const bf16x8*)&lA[(wr + i * 16 + q) * 32 + rdoff];
    #pragma unroll
    for (int j = 0; j < 4; ++j)
      bf[j] = *(const bf16x8*)&lB[(wc + j * 16 + q) * 32 + rdoff];
    #pragma unroll
    for (int i = 0; i < 4; ++i)
      #pragma unroll
      for (int j = 0; j < 4; ++j)
        acc[i][j] = __builtin_amdgcn_mfma_f32_16x16x32_bf16(af[i], bf[j], acc[i][j], 0, 0, 0);
  }
  const int rg = cg * 4;
  #pragma unroll
  for (int i = 0; i < 4; ++i) {
    #pragma unroll
    for (int j = 0; j < 4; ++j) {
      int col = n0 + wc + j * 16 + q;
      float bv = bias[col];
      float scl = (QS && col < 128) ? 0.25f : 1.f;
      #pragma unroll
      for (int jj = 0; jj < 4; ++jj) {
        int row = row0 + wr + i * 16 + rg + jj;
        float v = acc[i][j][jj] + bv;
        if (ACT == 1) v = 0.5f * v * (1.f + erff(v * 0.70710678118654752f));
        if (QS) v *= scl;
        if (RESID) ((float*)outp)[(size_t)row * N + col] += v;
        else ((u16*)outp)[(size_t)row * N + col] = f2bf(v);
      }
    }
  }
}

// ---------------------------------------------------------------- attention (32x32 MFMA flash)
// grid (NHEAD, BATCH), 256 threads = 4 waves. qkv: [T][384] bf16 (q pre-scaled by 0.25).
// Per wave: 32-q-row tiles. S^T[32k][32q] = mfma_32x32x16(Kfrag, Qfrag): one mfma, K=16=d.
// D-layout: col=lane&31 (=q), row=(reg&3)+8*(reg>>2)+4*(lane>>5) (=k) -> lane-local softmax
// (15 local fmax + 1 shfl_xor(32)). O^T += mfma(Vt_frag, P_frag) x2 (k halves).
// P frags assembled via 8 cvt_pk + 8 shfl_xor(32) + hi-select.
#define VSTR2 296   // Vt row stride (u16): 592B, 16B-aligned
__global__ __launch_bounds__(256)
void k_attn(const u16* __restrict__ qkv, const int* __restrict__ mask,
            u16* __restrict__ out) {
  int h = blockIdx.x, b = blockIdx.y;
  __shared__ __align__(16) u16 Klin[9 * 512];     // frag-linear K: [tile][lane][8]
  __shared__ __align__(16) u16 Vt[16 * VSTR2];    // V transposed: [d][k]
  __shared__ int part[4];
  const int tid = threadIdx.x;
  int mv = (mask[b * SEQL + tid] != 0) ? 1 : 0;
  #pragma unroll
  for (int o = 32; o; o >>= 1) mv += __shfl_xor(mv, o);
  if ((tid & 63) == 0) part[tid >> 6] = mv;
  // K staging: element K[r][d] -> Klin[(r>>5)*512 + (d>>3)*256 + (r&31)*8 + (d&7)]
  for (int idx = tid; idx < 576; idx += 256) {
    int r = idx >> 1, h2 = idx & 1;
    uint4 val = make_uint4(0, 0, 0, 0);
    if (r < NPOS)
      val = *(const uint4*)&qkv[((size_t)(b * NPOS + r)) * 384 + h * 16 + 128 + h2 * 8];
    *(uint4*)&Klin[(r >> 5) * 512 + h2 * 256 + (r & 31) * 8] = val;
  }
  // V staging: Vt[d][r] = V[r][d]
  for (int r = tid; r < 288; r += 256) {
    u16 tmp[16];
    if (r < NPOS) {
      const u16* vp = &qkv[((size_t)(b * NPOS + r)) * 384 + h * 16 + 256];
      *(uint4*)&tmp[0] = *(const uint4*)&vp[0];
      *(uint4*)&tmp[8] = *(const uint4*)&vp[8];
    } else {
      #pragma unroll
      for (int d = 0; d < 16; ++d) tmp[d] = 0;
    }
    #pragma unroll
    for (int d = 0; d < 16; ++d) Vt[d * VSTR2 + r] = tmp[d];
  }
  __syncthreads();
  const int nvalid = part[0] + part[1] + part[2] + part[3] + 3;
  const int ktiles = (nvalid + 31) >> 5;
  const int wave = tid >> 6, lane = tid & 63;
  const int q5 = lane & 31, hi = lane >> 5;
  const f32x16 zf = {};
  for (int qt = wave; qt < 9; qt += 4) {
    int qrow = qt * 32 + q5;
    int qr = (qrow < NPOS) ? qrow : (NPOS - 1);
    bf16x8 qf = *(const bf16x8*)&qkv[((size_t)(b * NPOS + qr)) * 384 + h * 16 + hi * 8];
    float m = -1e30f, l = 0.f;
    f32x16 acc = {};
    for (int kt = 0; kt < ktiles; ++kt) {
      bf16x8 kf = *(const bf16x8*)&Klin[kt * 512 + lane * 8];
      f32x16 s4 = __builtin_amdgcn_mfma_f32_32x32x16_bf16(kf, qf, zf, 0, 0, 0);
      float p[16];
      float tmax = -1e30f;
      #pragma unroll
      for (int r = 0; r < 16; ++r) {
        int kr = kt * 32 + (r & 3) + 8 * (r >> 2) + 4 * hi;
        float v = (kr < nvalid) ? s4[r] : -1e30f;
        p[r] = v;
        tmax = fmaxf(tmax, v);
      }
      tmax = fmaxf(tmax, __shfl_xor(tmax, 32));
      float mnew = fmaxf(m, tmax);
      float fac = __expf(m - mnew);
      float tsum = 0.f;
      #pragma unroll
      for (int r = 0; r < 16; ++r) { p[r] = __expf(p[r] - mnew); tsum += p[r]; }
      tsum += __shfl_xor(tsum, 32);
      l = l * fac + tsum;
      m = mnew;
      #pragma unroll
      for (int r = 0; r < 8; ++r) acc[r] *= fac;   // regs 8-15 stay 0 (A rows >=16 are 0)
      // pack P to bf16 pairs: w[i] = (p[2i], p[2i+1]) -> k offsets per table
      u32 w[8], xw[8];
      #pragma unroll
      for (int i = 0; i < 8; ++i)
        asm("v_cvt_pk_bf16_f32 %0, %1, %2" : "=v"(w[i]) : "v"(p[2 * i]), "v"(p[2 * i + 1]));
      #pragma unroll
      for (int i = 0; i < 8; ++i) xw[i] = (u32)__shfl_xor((int)w[i], 32);
      union { u32 u[4]; bf16x8 v; } f1, f2;
      if (hi) {
        f1.u[0] = xw[2]; f1.u[1] = xw[3]; f1.u[2] = w[2]; f1.u[3] = w[3];
        f2.u[0] = xw[6]; f2.u[1] = xw[7]; f2.u[2] = w[6]; f2.u[3] = w[7];
      } else {
        f1.u[0] = w[0]; f1.u[1] = w[1]; f1.u[2] = xw[0]; f1.u[3] = xw[1];
        f2.u[0] = w[4]; f2.u[1] = w[5]; f2.u[2] = xw[4]; f2.u[3] = xw[5];
      }
      bf16x8 vf0 = {}, vf1 = {};
      if (q5 < 16) {
        vf0 = *(const bf16x8*)&Vt[q5 * VSTR2 + kt * 32 + hi * 8];
        vf1 = *(const bf16x8*)&Vt[q5 * VSTR2 + kt * 32 + 16 + hi * 8];
      }
      acc = __builtin_amdgcn_mfma_f32_32x32x16_bf16(vf0, f1.v, acc, 0, 0, 0);
      acc = __builtin_amdgcn_mfma_f32_32x32x16_bf16(vf1, f2.v, acc, 0, 0, 0);
    }
    if (qrow < NPOS) {
      float linv = 1.f / l;
      u16* op = &out[((size_t)(b * NPOS + qrow)) * HD + h * 16];
      // lane holds d = {4hi..4hi+3} (regs 0-3) and {8+4hi..} (regs 4-7)
      u32 w0 = (u32)f2bf(acc[0] * linv) | ((u32)f2bf(acc[1] * linv) << 16);
      u32 w1 = (u32)f2bf(acc[2] * linv) | ((u32)f2bf(acc[3] * linv) << 16);
      u32 w2 = (u32)f2bf(acc[4] * linv) | ((u32)f2bf(acc[5] * linv) << 16);
      u32 w3 = (u32)f2bf(acc[6] * linv) | ((u32)f2bf(acc[7] * linv) << 16);
      *(uint2*)&op[4 * hi] = make_uint2(w0, w1);
      *(uint2*)&op[8 + 4 * hi] = make_uint2(w2, w3);
    }
  }
}

// ---------------------------------------------------------------- head
__global__ __launch_bounds__(128)
void k_head(const float* __restrict__ x, const float* __restrict__ bw,
            const float* __restrict__ bb, const float* __restrict__ cw,
            const float* __restrict__ cb, float* __restrict__ dout) {
  int b = blockIdx.x, n = threadIdx.x;
  __shared__ float lat[HD];
  __shared__ float redp[2], redss[2];
  float lv = x[((size_t)b * NPOS) * HD + n];
  lat[n] = lv;
  __syncthreads();
  float t = 0.f;
  for (int k = 0; k < HD; ++k) t += lat[k] * bw[k * HD + n];
  t += bb[n];
  t = fmaxf(t, 0.f);
  float p = t * cw[n];
  float ss = lv * lv;
  #pragma unroll
  for (int o = 32; o; o >>= 1) { p += __shfl_xor(p, o); ss += __shfl_xor(ss, o); }
  if ((n & 63) == 0) { redp[n >> 6] = p; redss[n >> 6] = ss; }
  __syncthreads();
  float psum = redp[0] + redp[1];
  float ssum = redss[0] + redss[1];
  if (n == 0) dout[b] = psum + cb[0];
  float nrm = fmaxf(sqrtf(ssum), 1e-12f);
  dout[256 + (size_t)b * HD + n] = lv / nrm;
}

// ---------------------------------------------------------------- launch
extern "C" void kernel_launch(void* const* d_in, const int* in_sizes, int n_in,
                              void* d_out, int out_size, void* d_ws, size_t ws_size,
                              hipStream_t stream) {
  const int* item_seq = (const int*)d_in[0];
  const int* action_seq = (const int*)d_in[1];
  const int* time_diff = (const int*)d_in[2];
  const int* mask = (const int*)d_in[3];
  const int* u_cv = (const int*)d_in[4];
  const int* u_cl = (const int*)d_in[5];
  const float* u_num = (const float*)d_in[6];
  const int* i_cv = (const int*)d_in[7];
  const int* i_cl = (const int*)d_in[8];
  const float* i_num = (const float*)d_in[9];
  const float* item_t = (const float*)d_in[10];
  const float* act_t = (const float*)d_in[11];
  const float* time_t = (const float*)d_in[12];
  const float* cat_t = (const float*)d_in[13];
  const float* num_W = (const float*)d_in[14];
  const float* gtok = (const float*)d_in[15];
  const float* ln1_g = (const float*)d_in[16];
  const float* ln1_b = (const float*)d_in[17];
  const float* qkv_w = (const float*)d_in[18];
  const float* qkv_b = (const float*)d_in[19];
  const float* out_w = (const float*)d_in[20];
  const float* out_b = (const float*)d_in[21];
  const float* w1 = (const float*)d_in[22];
  const float* b1 = (const float*)d_in[23];
  const float* w2 = (const float*)d_in[24];
  const float* b2 = (const float*)d_in[25];
  const float* ln2_g = (const float*)d_in[26];
  const float* ln2_b = (const float*)d_in[27];
  const float* bott_w = (const float*)d_in[28];
  const float* bott_b = (const float*)d_in[29];
  const float* cls_w = (const float*)d_in[30];
  const float* cls_b = (const float*)d_in[31];

  // workspace layout (bytes)
  const size_t off_x   = 0;                    // TTOK*128 f32  = 33,947,648
  const size_t off_src = 33947648;             // TTOK*128 bf16 = 16,973,824
  const size_t off_big = 50921472;             // TTOK*512 bf16 = 67,895,296
  const size_t off_wT  = 118816768;            // 786,432 elems bf16
  const size_t need    = 120389632;
  if (ws_size < need) {
    fprintf(stderr, "kernel_launch: ws_size %zu < needed %zu\n", ws_size, need);
    return;
  }
  char* ws = (char*)d_ws;
  float* x   = (float*)(ws + off_x);
  u16* src   = (u16*)(ws + off_src);
  u16* big   = (u16*)(ws + off_big);
  u16* wT    = (u16*)(ws + off_wT);
  u16* qkvT  = wT;                 // [4][384][128]
  u16* outT  = wT + 196608;        // [4][128][128]
  u16* w1T   = wT + 262144;        // [4][512][128]
  u16* w2T   = wT + 524288;        // [4][128][512]

  k_transpose<<<(4 * 128 * 384 + 255) / 256, 256, 0, stream>>>(qkv_w, qkvT, 4, 128, 384);
  k_transpose<<<(4 * 128 * 128 + 255) / 256, 256, 0, stream>>>(out_w, outT, 4, 128, 128);
  k_transpose<<<(4 * 128 * 512 + 255) / 256, 256, 0, stream>>>(w1, w1T, 4, 128, 512);
  k_transpose<<<(4 * 512 * 128 + 255) / 256, 256, 0, stream>>>(w2, w2T, 4, 512, 128);

  k_build<<<dim3(NPOS, BATCH), 128, 0, stream>>>(
      item_seq, action_seq, time_diff, u_cv, u_cl, u_num, i_cv, i_cl, i_num,
      item_t, act_t, time_t, cat_t, num_W, gtok, x);

  const int rt = TTOK / 128;  // 518
  for (int dd = 0; dd < DEPTH; ++dd) {
    k_ln<<<TTOK / 4, 256, 0, stream>>>(x, ln1_g + dd * HD, ln1_b + dd * HD, src);
    k_gemm<0, false, true><<<dim3(rt, 3), 256, 0, stream>>>(src, qkvT + dd * 49152, qkv_b + dd * 384, big, 128, 384);
    k_attn<<<dim3(NHEAD, BATCH), 256, 0, stream>>>(big, mask, src);
    k_gemm<0, true, false><<<dim3(rt, 1), 256, 0, stream>>>(src, outT + dd * 16384, out_b + dd * HD, x, 128, 128);
    k_ln<<<TTOK / 4, 256, 0, stream>>>(x, ln2_g + dd * HD, ln2_b + dd * HD, src);
    k_gemm<1, false, false><<<dim3(rt, 4), 256, 0, stream>>>(src, w1T + dd * 65536, b1 + dd * FF, big, 128, 512);
    k_gemm<0, true, false><<<dim3(rt, 1), 256, 0, stream>>>(big, w2T + dd * 65536, b2 + dd * HD, x, 512, 128);
  }

  k_head<<<BATCH, 128, 0, stream>>>(x, bott_w, bott_b, cls_w, cls_b, (float*)d_out);
}